// Round 2
// baseline (238.096 us; speedup 1.0000x reference)
//
#include <hip/hip_runtime.h>

// VQ-VAE forward via bf16 MFMA distance scan.
//   score(token,code) = dot(x,w) - ||w||^2/2   (maximize == argmin distance)
//   dist_best = -2*score_best;  SSE = sum(xsq) + sum(dist_best)
//
// R5: NO LDS staging. vq_init stores the codebook pre-swizzled in wave-read
//     order; vq_main streams B-fragments directly from L2 with lane-linear
//     16B loads (two 1KB wave-loads per 16-code tile), 1-deep prefetch.
//     No barriers in the hot loop; waves fully independent. 32 tokens/wave,
//     grid 1024 (4 blocks/CU, 16 waves/CU).
//
// ws layout: [0,4096) u32 counts[1024] | [4096,4104) double sse
//            [5120,5124) u32 ticket
//            [8192,12288) float wnh[1024] (= -0.5||w||^2)
//            [16384,16384+131072) bf16 W_swz: uint4[K/16][8][64] wave-read order

typedef __bf16          bf16x8  __attribute__((ext_vector_type(8)));
typedef float           f32x4   __attribute__((ext_vector_type(4)));
typedef unsigned short  ushortx8 __attribute__((ext_vector_type(8)));

constexpr int D = 64;
constexpr int K = 1024;
constexpr int TOKB = 128;             // tokens per block (32/wave x 4 waves)

__device__ __forceinline__ unsigned short f2bf(float f) {
  unsigned u = __builtin_bit_cast(unsigned, f);
  u = (u + 0x7fffu + ((u >> 16) & 1u)) >> 16;  // RNE
  return (unsigned short)u;
}

__global__ __launch_bounds__(64) void vq_init(const float* __restrict__ W,
                                              unsigned* __restrict__ counts,
                                              float* __restrict__ wnh,
                                              double* __restrict__ sse,
                                              unsigned* __restrict__ ticket,
                                              uint4* __restrict__ wswz) {
  const int c = blockIdx.x * 64 + threadIdx.x;  // 0..1023
  const int ct = c >> 4, cnl = c & 15;
  const float4* row = reinterpret_cast<const float4*>(W + c * D);
  float s = 0.f;
#pragma unroll
  for (int p = 0; p < 8; ++p) {
    float4 v0 = row[2 * p], v1 = row[2 * p + 1];
    s = fmaf(v0.x, v0.x, s); s = fmaf(v0.y, v0.y, s);
    s = fmaf(v0.z, v0.z, s); s = fmaf(v0.w, v0.w, s);
    s = fmaf(v1.x, v1.x, s); s = fmaf(v1.y, v1.y, s);
    s = fmaf(v1.z, v1.z, s); s = fmaf(v1.w, v1.w, s);
    ushortx8 pk;
    pk[0] = f2bf(v0.x); pk[1] = f2bf(v0.y); pk[2] = f2bf(v0.z); pk[3] = f2bf(v0.w);
    pk[4] = f2bf(v1.x); pk[5] = f2bf(v1.y); pk[6] = f2bf(v1.z); pk[7] = f2bf(v1.w);
    // swizzle: slot such that wave read b0/b1 at [ct*128 + half*64 + lane] is
    // lane-linear: lane = q*16 + cnl holds k-part (half*4+q) of code cnl.
    const int half = p >> 2, q = p & 3;
    wswz[ct * 128 + half * 64 + q * 16 + cnl] = __builtin_bit_cast(uint4, pk);
  }
  wnh[c] = -0.5f * s;
  counts[c] = 0u;
  if (c == 0) { *sse = 0.0; *ticket = 0u; }
}

// 256 threads = 4 waves; 32 tokens/wave (2 A-tiles of 16) -> 128 tokens/block.
__global__ __launch_bounds__(256, 4) void vq_main(const float* __restrict__ x,
                                                  const float* __restrict__ Wf,
                                                  const uint4* __restrict__ wswz,
                                                  const float* __restrict__ wnh,
                                                  unsigned* __restrict__ counts,
                                                  double* __restrict__ sse,
                                                  unsigned* __restrict__ ticket,
                                                  float* __restrict__ out,
                                                  int n_tokens) {
  __shared__ unsigned s_hist[K];       // 4 KB
  __shared__ unsigned s_idx[TOKB];     // 0.5 KB
  __shared__ float s_red[4];
  __shared__ unsigned s_ured[4];
  __shared__ unsigned s_last;

  const int tid = threadIdx.x;
  const int wv = tid >> 6, lane = tid & 63;
  const int g = lane >> 4, nl = lane & 15;
  const int tokwg = blockIdx.x * TOKB;

  for (int i = tid; i < K; i += 256) s_hist[i] = 0u;
  __syncthreads();   // hist zero visible before epilogue atomics

  // A fragments: lane holds A[m=lane&15][k=(lane>>4)*8+j]; 2 token tiles.
  bf16x8 afrag[2][2];
  float xsq = 0.f;
#pragma unroll
  for (int tt = 0; tt < 2; ++tt) {
#pragma unroll
    for (int s = 0; s < 2; ++s) {
      const float* px = x + (size_t)(tokwg + wv * 32 + tt * 16 + nl) * D + s * 32 + g * 8;
      float4 v0 = *reinterpret_cast<const float4*>(px);
      float4 v1 = *reinterpret_cast<const float4*>(px + 4);
      xsq = fmaf(v0.x, v0.x, xsq); xsq = fmaf(v0.y, v0.y, xsq);
      xsq = fmaf(v0.z, v0.z, xsq); xsq = fmaf(v0.w, v0.w, xsq);
      xsq = fmaf(v1.x, v1.x, xsq); xsq = fmaf(v1.y, v1.y, xsq);
      xsq = fmaf(v1.z, v1.z, xsq); xsq = fmaf(v1.w, v1.w, xsq);
      ushortx8 p;
      p[0] = f2bf(v0.x); p[1] = f2bf(v0.y); p[2] = f2bf(v0.z); p[3] = f2bf(v0.w);
      p[4] = f2bf(v1.x); p[5] = f2bf(v1.y); p[6] = f2bf(v1.z); p[7] = f2bf(v1.w);
      afrag[tt][s] = __builtin_bit_cast(bf16x8, p);
    }
  }

  float best[2][4];
  unsigned bidx[2][4];
#pragma unroll
  for (int tt = 0; tt < 2; ++tt)
#pragma unroll
    for (int j = 0; j < 4; ++j) { best[tt][j] = -3.0e38f; bidx[tt][j] = 0u; }

  // ---- barrier-free scan over all 1024 codes, 16 per tile, from L2 ----
  // 1-deep prefetch: next tile's loads are in flight during current MFMAs.
  uint4 nb0 = wswz[lane];
  uint4 nb1 = wswz[64 + lane];
  float nw0 = wnh[nl];
#pragma unroll 4
  for (int ct = 0; ct < K / 16; ++ct) {
    const uint4 cb0 = nb0, cb1 = nb1;
    const float w0 = nw0;
    if (ct < K / 16 - 1) {
      nb0 = wswz[(ct + 1) * 128 + lane];
      nb1 = wswz[(ct + 1) * 128 + 64 + lane];
      nw0 = wnh[(ct + 1) * 16 + nl];
    }
    const bf16x8 b0 = __builtin_bit_cast(bf16x8, cb0);
    const bf16x8 b1 = __builtin_bit_cast(bf16x8, cb1);
    const unsigned code0 = (unsigned)(ct * 16 + nl);
    f32x4 acc[2];
#pragma unroll
    for (int tt = 0; tt < 2; ++tt) {
      acc[tt] = (f32x4){w0, w0, w0, w0};  // C init = -||w||^2/2 (per col)
      acc[tt] = __builtin_amdgcn_mfma_f32_16x16x32_bf16(afrag[tt][0], b0, acc[tt], 0, 0, 0);
      acc[tt] = __builtin_amdgcn_mfma_f32_16x16x32_bf16(afrag[tt][1], b1, acc[tt], 0, 0, 0);
    }
#pragma unroll
    for (int tt = 0; tt < 2; ++tt)
#pragma unroll
      for (int j = 0; j < 4; ++j) {
        if (acc[tt][j] > best[tt][j]) { best[tt][j] = acc[tt][j]; bidx[tt][j] = code0; }
      }
  }

  // Cross-lane argmax over the 16 cols; C/D row = 4*g+j, col = nl.
  float ddist = 0.f;
#pragma unroll
  for (int tt = 0; tt < 2; ++tt) {
#pragma unroll
    for (int j = 0; j < 4; ++j) {
      float b = best[tt][j];
      unsigned bi = bidx[tt][j];
#pragma unroll
      for (int off = 1; off < 16; off <<= 1) {
        float ob = __shfl_xor(b, off, 64);
        unsigned oi = __shfl_xor(bi, off, 64);
        if (ob > b || (ob == b && oi < bi)) { b = ob; bi = oi; }
      }
      if (nl == 0) {
        int tl = wv * 32 + tt * 16 + 4 * g + j;
        s_idx[tl] = bi;
        atomicAdd(&s_hist[bi], 1u);
        ddist = fmaf(-2.0f, b, ddist);  // dist = wsq - 2*dot >= 0
      }
    }
  }

  // Block-reduce SSE contribution: sum(x^2) + sum(dist_best).
  float sv = xsq + ddist;
#pragma unroll
  for (int off = 32; off > 0; off >>= 1) sv += __shfl_down(sv, off, 64);
  if (lane == 0) s_red[wv] = sv;
  __syncthreads();  // also publishes s_idx / orders s_hist atomics
  if (tid == 0) atomicAdd(sse, (double)((s_red[0] + s_red[1]) + (s_red[2] + s_red[3])));

  for (int i = tid; i < K; i += 256) {
    unsigned h = s_hist[i];
    if (h) atomicAdd(&counts[i], h);
  }

  // out = W[idx] (fp32 gather; == x + (q - x) to <=1 ulp).
  const int d4 = tid & 15;
#pragma unroll
  for (int tk = 0; tk < 8; ++tk) {
    int tl = tk * 16 + (tid >> 4);
    unsigned ci = s_idx[tl];
    float4 q = *reinterpret_cast<const float4*>(Wf + ci * D + d4 * 4);
    *reinterpret_cast<float4*>(out + (size_t)(tokwg + tl) * D + d4 * 4) = q;
  }

  // ---- fused final: last block to finish does the tail reduction ----
  __threadfence();           // make this thread's counts/sse updates visible
  __syncthreads();
  if (tid == 0) {
    unsigned t = atomicAdd(ticket, 1u);
    s_last = (t == gridDim.x - 1) ? 1u : 0u;
  }
  __syncthreads();
  if (s_last) {
    __threadfence();
    const float inv_n = 1.0f / (float)n_tokens;
    float s = 0.f;
    unsigned u = 0;
    for (int c = tid; c < K; c += 256) {
      unsigned cnt = atomicAdd(&counts[c], 0u);  // coherent RMW read
      float p = (float)cnt * inv_n;
      s += p * logf(p + 1e-10f);
      u += (cnt >= 1u) ? 1u : 0u;
    }
#pragma unroll
    for (int off = 32; off > 0; off >>= 1) {
      s += __shfl_down(s, off, 64);
      u += __shfl_down(u, off, 64);
    }
    if (lane == 0) { s_red[wv] = s; s_ured[wv] = u; }
    __syncthreads();
    if (tid == 0) {
      double sv2 = atomicAdd(sse, 0.0);  // coherent read of final SSE
      float s2 = (s_red[0] + s_red[1]) + (s_red[2] + s_red[3]);
      unsigned u2 = s_ured[0] + s_ured[1] + s_ured[2] + s_ured[3];
      double mean = sv2 / ((double)n_tokens * (double)D);
      float* out_tail = out + (size_t)n_tokens * D;
      out_tail[0] = 3.0f * (float)mean;  // q_latent + 2*e_latent
      out_tail[1] = expf(-s2);           // perplexity
      out_tail[2] = (float)u2;           // usage
    }
  }
}

extern "C" void kernel_launch(void* const* d_in, const int* in_sizes, int n_in,
                              void* d_out, int out_size, void* d_ws, size_t ws_size,
                              hipStream_t stream) {
  const float* x = (const float*)d_in[0];
  const float* W = (const float*)d_in[1];
  float* out = (float*)d_out;

  unsigned* counts = (unsigned*)d_ws;
  double* sse = (double*)((char*)d_ws + 4096);
  unsigned* ticket = (unsigned*)((char*)d_ws + 5120);
  float* wnh = (float*)((char*)d_ws + 8192);
  uint4* wswz = (uint4*)((char*)d_ws + 16384);

  const int n_tokens = in_sizes[0] / D;  // 131072
  const int blocks = n_tokens / TOKB;    // 1024

  vq_init<<<K / 64, 64, 0, stream>>>(W, counts, wnh, sse, ticket, wswz);
  vq_main<<<blocks, 256, 0, stream>>>(x, W, wswz, wnh, counts, sse, ticket,
                                      out, n_tokens);
}

// Round 4
// 130.539 us; speedup vs baseline: 1.8239x; 1.8239x over previous
//
#include <hip/hip_runtime.h>

// VQ-VAE forward via bf16 MFMA distance scan.
//   score(token,code) = dot(x,w) - ||w||^2/2   (maximize == argmin distance)
//   dist_best = -2*score_best;  SSE = sum(xsq) + sum(dist_best)
//
// R7 == R6 resubmit (container infra failure last round, no kernel verdict).
//     Core change vs R5: no __threadfence() in the fused final. The fence
//     emitted buffer_wbl2+buffer_inv per wave per block -> L2 invalidate storm
//     that evicted the L2-resident codebook for all in-flight blocks (the
//     66->170us regression). Cross-block comms are device-scope atomic RMWs
//     at the coherence point; the pre-ticket __syncthreads drains vmcnt(0).
//     Also: wnh staged once to LDS, vq_init widened to 8 threads/code.
//
// ws layout: [0,4096) u32 counts[1024] | [4096,4104) double sse
//            [5120,5124) u32 ticket
//            [8192,12288) float wnh[1024] (= -0.5||w||^2)
//            [16384,16384+131072) bf16 W_swz: uint4[K/16][8][64] wave-read order

typedef __bf16          bf16x8  __attribute__((ext_vector_type(8)));
typedef float           f32x4   __attribute__((ext_vector_type(4)));
typedef unsigned short  ushortx8 __attribute__((ext_vector_type(8)));

constexpr int D = 64;
constexpr int K = 1024;
constexpr int TOKB = 128;             // tokens per block (32/wave x 4 waves)

__device__ __forceinline__ unsigned short f2bf(float f) {
  unsigned u = __builtin_bit_cast(unsigned, f);
  u = (u + 0x7fffu + ((u >> 16) & 1u)) >> 16;  // RNE
  return (unsigned short)u;
}

// 8 threads per code: thread (c,p) converts 32B of row c, shuffle-reduces ||w||^2.
__global__ __launch_bounds__(256) void vq_init(const float* __restrict__ W,
                                               unsigned* __restrict__ counts,
                                               float* __restrict__ wnh,
                                               double* __restrict__ sse,
                                               unsigned* __restrict__ ticket,
                                               uint4* __restrict__ wswz) {
  const int gid = blockIdx.x * 256 + threadIdx.x;  // 0..8191
  const int c = gid >> 3, p = gid & 7;
  const float4* row = reinterpret_cast<const float4*>(W + c * D);
  float4 v0 = row[2 * p], v1 = row[2 * p + 1];
  float s = 0.f;
  s = fmaf(v0.x, v0.x, s); s = fmaf(v0.y, v0.y, s);
  s = fmaf(v0.z, v0.z, s); s = fmaf(v0.w, v0.w, s);
  s = fmaf(v1.x, v1.x, s); s = fmaf(v1.y, v1.y, s);
  s = fmaf(v1.z, v1.z, s); s = fmaf(v1.w, v1.w, s);
  ushortx8 pk;
  pk[0] = f2bf(v0.x); pk[1] = f2bf(v0.y); pk[2] = f2bf(v0.z); pk[3] = f2bf(v0.w);
  pk[4] = f2bf(v1.x); pk[5] = f2bf(v1.y); pk[6] = f2bf(v1.z); pk[7] = f2bf(v1.w);
  // swizzle: wave read b0/b1 at [ct*128 + half*64 + lane], lane = q*16 + cnl.
  const int ct = c >> 4, cnl = c & 15, half = p >> 2, q = p & 3;
  wswz[ct * 128 + half * 64 + q * 16 + cnl] = __builtin_bit_cast(uint4, pk);
  // reduce ||w||^2 across the 8 lanes of this code (aligned 8-lane groups)
  s += __shfl_xor(s, 1, 64);
  s += __shfl_xor(s, 2, 64);
  s += __shfl_xor(s, 4, 64);
  if (p == 0) wnh[c] = -0.5f * s;
  if (gid < K) counts[gid] = 0u;
  if (gid == 0) { *sse = 0.0; *ticket = 0u; }
}

// 256 threads = 4 waves; 32 tokens/wave (2 A-tiles of 16) -> 128 tokens/block.
__global__ __launch_bounds__(256, 4) void vq_main(const float* __restrict__ x,
                                                  const float* __restrict__ Wf,
                                                  const uint4* __restrict__ wswz,
                                                  const float* __restrict__ wnh,
                                                  unsigned* __restrict__ counts,
                                                  double* __restrict__ sse,
                                                  unsigned* __restrict__ ticket,
                                                  float* __restrict__ out,
                                                  int n_tokens) {
  __shared__ unsigned s_hist[K];       // 4 KB
  __shared__ float s_wnh[K];           // 4 KB (-0.5||w||^2, LDS broadcast reads)
  __shared__ unsigned s_idx[TOKB];     // 0.5 KB
  __shared__ float s_red[4];
  __shared__ unsigned s_ured[4];
  __shared__ unsigned s_last;

  const int tid = threadIdx.x;
  const int wv = tid >> 6, lane = tid & 63;
  const int g = lane >> 4, nl = lane & 15;
  const int tokwg = blockIdx.x * TOKB;

  for (int i = tid; i < K; i += 256) {
    s_hist[i] = 0u;
    s_wnh[i] = wnh[i];
  }
  __syncthreads();   // hist zero + wnh visible

  // A fragments: lane holds A[m=lane&15][k=(lane>>4)*8+j]; 2 token tiles.
  bf16x8 afrag[2][2];
  float xsq = 0.f;
#pragma unroll
  for (int tt = 0; tt < 2; ++tt) {
#pragma unroll
    for (int s = 0; s < 2; ++s) {
      const float* px = x + (size_t)(tokwg + wv * 32 + tt * 16 + nl) * D + s * 32 + g * 8;
      float4 v0 = *reinterpret_cast<const float4*>(px);
      float4 v1 = *reinterpret_cast<const float4*>(px + 4);
      xsq = fmaf(v0.x, v0.x, xsq); xsq = fmaf(v0.y, v0.y, xsq);
      xsq = fmaf(v0.z, v0.z, xsq); xsq = fmaf(v0.w, v0.w, xsq);
      xsq = fmaf(v1.x, v1.x, xsq); xsq = fmaf(v1.y, v1.y, xsq);
      xsq = fmaf(v1.z, v1.z, xsq); xsq = fmaf(v1.w, v1.w, xsq);
      ushortx8 p;
      p[0] = f2bf(v0.x); p[1] = f2bf(v0.y); p[2] = f2bf(v0.z); p[3] = f2bf(v0.w);
      p[4] = f2bf(v1.x); p[5] = f2bf(v1.y); p[6] = f2bf(v1.z); p[7] = f2bf(v1.w);
      afrag[tt][s] = __builtin_bit_cast(bf16x8, p);
    }
  }

  float best[2][4];
  unsigned bidx[2][4];
#pragma unroll
  for (int tt = 0; tt < 2; ++tt)
#pragma unroll
    for (int j = 0; j < 4; ++j) { best[tt][j] = -3.0e38f; bidx[tt][j] = 0u; }

  // ---- barrier-free scan over all 1024 codes, 16 per tile, from L2 ----
  // 1-deep prefetch: next tile's B-loads are in flight during current MFMAs.
  uint4 nb0 = wswz[lane];
  uint4 nb1 = wswz[64 + lane];
#pragma unroll 4
  for (int ct = 0; ct < K / 16; ++ct) {
    const uint4 cb0 = nb0, cb1 = nb1;
    if (ct < K / 16 - 1) {
      nb0 = wswz[(ct + 1) * 128 + lane];
      nb1 = wswz[(ct + 1) * 128 + 64 + lane];
    }
    const float w0 = s_wnh[ct * 16 + nl];   // LDS broadcast, off the vmcnt path
    const bf16x8 b0 = __builtin_bit_cast(bf16x8, cb0);
    const bf16x8 b1 = __builtin_bit_cast(bf16x8, cb1);
    const unsigned code0 = (unsigned)(ct * 16 + nl);
    f32x4 acc[2];
#pragma unroll
    for (int tt = 0; tt < 2; ++tt) {
      acc[tt] = (f32x4){w0, w0, w0, w0};  // C init = -||w||^2/2 (per col)
      acc[tt] = __builtin_amdgcn_mfma_f32_16x16x32_bf16(afrag[tt][0], b0, acc[tt], 0, 0, 0);
      acc[tt] = __builtin_amdgcn_mfma_f32_16x16x32_bf16(afrag[tt][1], b1, acc[tt], 0, 0, 0);
    }
#pragma unroll
    for (int tt = 0; tt < 2; ++tt)
#pragma unroll
      for (int j = 0; j < 4; ++j) {
        if (acc[tt][j] > best[tt][j]) { best[tt][j] = acc[tt][j]; bidx[tt][j] = code0; }
      }
  }

  // Cross-lane argmax over the 16 cols; C/D row = 4*g+j, col = nl.
  float ddist = 0.f;
#pragma unroll
  for (int tt = 0; tt < 2; ++tt) {
#pragma unroll
    for (int j = 0; j < 4; ++j) {
      float b = best[tt][j];
      unsigned bi = bidx[tt][j];
#pragma unroll
      for (int off = 1; off < 16; off <<= 1) {
        float ob = __shfl_xor(b, off, 64);
        unsigned oi = __shfl_xor(bi, off, 64);
        if (ob > b || (ob == b && oi < bi)) { b = ob; bi = oi; }
      }
      if (nl == 0) {
        int tl = wv * 32 + tt * 16 + 4 * g + j;
        s_idx[tl] = bi;
        atomicAdd(&s_hist[bi], 1u);
        ddist = fmaf(-2.0f, b, ddist);  // dist = wsq - 2*dot >= 0
      }
    }
  }

  // Block-reduce SSE contribution: sum(x^2) + sum(dist_best).
  float sv = xsq + ddist;
#pragma unroll
  for (int off = 32; off > 0; off >>= 1) sv += __shfl_down(sv, off, 64);
  if (lane == 0) s_red[wv] = sv;
  __syncthreads();  // also publishes s_idx / orders s_hist atomics
  if (tid == 0) atomicAdd(sse, (double)((s_red[0] + s_red[1]) + (s_red[2] + s_red[3])));

  for (int i = tid; i < K; i += 256) {
    unsigned h = s_hist[i];
    if (h) atomicAdd(&counts[i], h);
  }

  // out = W[idx] (fp32 gather; == x + (q - x) to <=1 ulp).
  const int d4 = tid & 15;
#pragma unroll
  for (int tk = 0; tk < 8; ++tk) {
    int tl = tk * 16 + (tid >> 4);
    unsigned ci = s_idx[tl];
    float4 q = *reinterpret_cast<const float4*>(Wf + ci * D + d4 * 4);
    *reinterpret_cast<float4*>(out + (size_t)(tokwg + tl) * D + d4 * 4) = q;
  }

  // ---- fused final: last block to finish does the tail reduction ----
  // NO __threadfence here: counts/sse updates are device-scope atomic RMWs
  // (coherent point); the compiler's s_waitcnt vmcnt(0) before s_barrier
  // guarantees they are issued+complete before the ticket RMW below. An
  // agent fence would buffer_inv the XCD L2 and stall every in-flight
  // block (the R4/R5 regression).
  __syncthreads();
  if (tid == 0) {
    unsigned t = atomicAdd(ticket, 1u);
    s_last = (t == gridDim.x - 1) ? 1u : 0u;
  }
  __syncthreads();
  if (s_last) {
    const float inv_n = 1.0f / (float)n_tokens;
    float s = 0.f;
    unsigned u = 0;
    for (int c = tid; c < K; c += 256) {
      unsigned cnt = atomicAdd(&counts[c], 0u);  // coherent RMW read
      float p = (float)cnt * inv_n;
      s += p * logf(p + 1e-10f);
      u += (cnt >= 1u) ? 1u : 0u;
    }
#pragma unroll
    for (int off = 32; off > 0; off >>= 1) {
      s += __shfl_down(s, off, 64);
      u += __shfl_down(u, off, 64);
    }
    if (lane == 0) { s_red[wv] = s; s_ured[wv] = u; }
    __syncthreads();
    if (tid == 0) {
      double sv2 = atomicAdd(sse, 0.0);  // coherent read of final SSE
      float s2 = (s_red[0] + s_red[1]) + (s_red[2] + s_red[3]);
      unsigned u2 = s_ured[0] + s_ured[1] + s_ured[2] + s_ured[3];
      double mean = sv2 / ((double)n_tokens * (double)D);
      float* out_tail = out + (size_t)n_tokens * D;
      out_tail[0] = 3.0f * (float)mean;  // q_latent + 2*e_latent
      out_tail[1] = expf(-s2);           // perplexity
      out_tail[2] = (float)u2;           // usage
    }
  }
}

extern "C" void kernel_launch(void* const* d_in, const int* in_sizes, int n_in,
                              void* d_out, int out_size, void* d_ws, size_t ws_size,
                              hipStream_t stream) {
  const float* x = (const float*)d_in[0];
  const float* W = (const float*)d_in[1];
  float* out = (float*)d_out;

  unsigned* counts = (unsigned*)d_ws;
  double* sse = (double*)((char*)d_ws + 4096);
  unsigned* ticket = (unsigned*)((char*)d_ws + 5120);
  float* wnh = (float*)((char*)d_ws + 8192);
  uint4* wswz = (uint4*)((char*)d_ws + 16384);

  const int n_tokens = in_sizes[0] / D;  // 131072
  const int blocks = n_tokens / TOKB;    // 1024

  vq_init<<<K * 8 / 256, 256, 0, stream>>>(W, counts, wnh, sse, ticket, wswz);
  vq_main<<<blocks, 256, 0, stream>>>(x, W, wswz, wnh, counts, sse, ticket,
                                      out, n_tokens);
}

// Round 5
// 123.658 us; speedup vs baseline: 1.9254x; 1.0556x over previous
//
#include <hip/hip_runtime.h>

// VQ-VAE forward via bf16 MFMA distance scan.
//   score(token,code) = dot(x,w) - ||w||^2/2   (maximize == argmin distance)
//   dist_best = -2*score_best;  SSE = sum(xsq) + sum(dist_best)
//
// R8: latency fix. 64 tokens/wave (4 A-tile-chains, TOKB=256, grid 512) doubles
//     work per B-load; 4-slot statically-unrolled prefetch ring keeps 3 tiles
//     (6 loads) in flight -> ~350cyc cover vs ~200cyc L2 latency. No fences
//     (R7 lesson: agent fence = XCD L2 invalidate storm). launch_bounds(256,2)
//     frees VGPR budget (grid-limited occupancy anyway).
//
// ws layout: [0,4096) u32 counts[1024] | [4096,4104) double sse
//            [5120,5124) u32 ticket
//            [8192,12288) float wnh[1024] (= -0.5||w||^2)
//            [16384,16384+131072) bf16 W_swz: uint4[K/16][8][64] wave-read order

typedef __bf16          bf16x8  __attribute__((ext_vector_type(8)));
typedef float           f32x4   __attribute__((ext_vector_type(4)));
typedef unsigned short  ushortx8 __attribute__((ext_vector_type(8)));

constexpr int D = 64;
constexpr int K = 1024;
constexpr int TOKB = 256;             // tokens per block (64/wave x 4 waves)

__device__ __forceinline__ unsigned short f2bf(float f) {
  unsigned u = __builtin_bit_cast(unsigned, f);
  u = (u + 0x7fffu + ((u >> 16) & 1u)) >> 16;  // RNE
  return (unsigned short)u;
}

// 8 threads per code: thread (c,p) converts 32B of row c, shuffle-reduces ||w||^2.
__global__ __launch_bounds__(256) void vq_init(const float* __restrict__ W,
                                               unsigned* __restrict__ counts,
                                               float* __restrict__ wnh,
                                               double* __restrict__ sse,
                                               unsigned* __restrict__ ticket,
                                               uint4* __restrict__ wswz) {
  const int gid = blockIdx.x * 256 + threadIdx.x;  // 0..8191
  const int c = gid >> 3, p = gid & 7;
  const float4* row = reinterpret_cast<const float4*>(W + c * D);
  float4 v0 = row[2 * p], v1 = row[2 * p + 1];
  float s = 0.f;
  s = fmaf(v0.x, v0.x, s); s = fmaf(v0.y, v0.y, s);
  s = fmaf(v0.z, v0.z, s); s = fmaf(v0.w, v0.w, s);
  s = fmaf(v1.x, v1.x, s); s = fmaf(v1.y, v1.y, s);
  s = fmaf(v1.z, v1.z, s); s = fmaf(v1.w, v1.w, s);
  ushortx8 pk;
  pk[0] = f2bf(v0.x); pk[1] = f2bf(v0.y); pk[2] = f2bf(v0.z); pk[3] = f2bf(v0.w);
  pk[4] = f2bf(v1.x); pk[5] = f2bf(v1.y); pk[6] = f2bf(v1.z); pk[7] = f2bf(v1.w);
  // swizzle: wave read b0/b1 at [ct*128 + half*64 + lane], lane = q*16 + cnl.
  const int ct = c >> 4, cnl = c & 15, half = p >> 2, q = p & 3;
  wswz[ct * 128 + half * 64 + q * 16 + cnl] = __builtin_bit_cast(uint4, pk);
  // reduce ||w||^2 across the 8 lanes of this code (aligned 8-lane groups)
  s += __shfl_xor(s, 1, 64);
  s += __shfl_xor(s, 2, 64);
  s += __shfl_xor(s, 4, 64);
  if (p == 0) wnh[c] = -0.5f * s;
  if (gid < K) counts[gid] = 0u;
  if (gid == 0) { *sse = 0.0; *ticket = 0u; }
}

// 256 threads = 4 waves; 64 tokens/wave (4 A-tiles of 16) -> 256 tokens/block.
__global__ __launch_bounds__(256, 2) void vq_main(const float* __restrict__ x,
                                                  const float* __restrict__ Wf,
                                                  const uint4* __restrict__ wswz,
                                                  const float* __restrict__ wnh,
                                                  unsigned* __restrict__ counts,
                                                  double* __restrict__ sse,
                                                  unsigned* __restrict__ ticket,
                                                  float* __restrict__ out,
                                                  int n_tokens) {
  __shared__ unsigned s_hist[K];       // 4 KB
  __shared__ float s_wnh[K];           // 4 KB (-0.5||w||^2, LDS broadcast reads)
  __shared__ unsigned s_idx[TOKB];     // 1 KB
  __shared__ float s_red[4];
  __shared__ unsigned s_ured[4];
  __shared__ unsigned s_last;

  const int tid = threadIdx.x;
  const int wv = tid >> 6, lane = tid & 63;
  const int g = lane >> 4, nl = lane & 15;
  const int tokwg = blockIdx.x * TOKB;

  for (int i = tid; i < K; i += 256) {
    s_hist[i] = 0u;
    s_wnh[i] = wnh[i];
  }
  __syncthreads();   // hist zero + wnh visible

  // A fragments: lane holds A[m=lane&15][k=(lane>>4)*8+j]; 4 token tiles.
  bf16x8 afrag[4][2];
  float xsq = 0.f;
#pragma unroll
  for (int tt = 0; tt < 4; ++tt) {
#pragma unroll
    for (int s = 0; s < 2; ++s) {
      const float* px = x + (size_t)(tokwg + wv * 64 + tt * 16 + nl) * D + s * 32 + g * 8;
      float4 v0 = *reinterpret_cast<const float4*>(px);
      float4 v1 = *reinterpret_cast<const float4*>(px + 4);
      xsq = fmaf(v0.x, v0.x, xsq); xsq = fmaf(v0.y, v0.y, xsq);
      xsq = fmaf(v0.z, v0.z, xsq); xsq = fmaf(v0.w, v0.w, xsq);
      xsq = fmaf(v1.x, v1.x, xsq); xsq = fmaf(v1.y, v1.y, xsq);
      xsq = fmaf(v1.z, v1.z, xsq); xsq = fmaf(v1.w, v1.w, xsq);
      ushortx8 p;
      p[0] = f2bf(v0.x); p[1] = f2bf(v0.y); p[2] = f2bf(v0.z); p[3] = f2bf(v0.w);
      p[4] = f2bf(v1.x); p[5] = f2bf(v1.y); p[6] = f2bf(v1.z); p[7] = f2bf(v1.w);
      afrag[tt][s] = __builtin_bit_cast(bf16x8, p);
    }
  }

  float best[4][4];
  unsigned bidx[4][4];
#pragma unroll
  for (int tt = 0; tt < 4; ++tt)
#pragma unroll
    for (int j = 0; j < 4; ++j) { best[tt][j] = -3.0e38f; bidx[tt][j] = 0u; }

  // One 16-code tile: 4 MFMA chains + argmax bookkeeping.
  auto process = [&](int ct, uint4 cb0, uint4 cb1) {
    const float w0 = s_wnh[ct * 16 + nl];   // LDS broadcast, off the vmcnt path
    const bf16x8 b0 = __builtin_bit_cast(bf16x8, cb0);
    const bf16x8 b1 = __builtin_bit_cast(bf16x8, cb1);
    const unsigned code0 = (unsigned)(ct * 16 + nl);
#pragma unroll
    for (int tt = 0; tt < 4; ++tt) {
      f32x4 acc = (f32x4){w0, w0, w0, w0};  // C init = -||w||^2/2 (per col)
      acc = __builtin_amdgcn_mfma_f32_16x16x32_bf16(afrag[tt][0], b0, acc, 0, 0, 0);
      acc = __builtin_amdgcn_mfma_f32_16x16x32_bf16(afrag[tt][1], b1, acc, 0, 0, 0);
#pragma unroll
      for (int j = 0; j < 4; ++j) {
        if (acc[j] > best[tt][j]) { best[tt][j] = acc[j]; bidx[tt][j] = code0; }
      }
    }
  };

  // ---- barrier-free scan over all 1024 codes, 16 per tile, from L2 ----
  // 4-slot prefetch ring, statically unrolled: while tile ct is consumed,
  // tiles ct+1..ct+3 (6 loads) are in flight -> covers ~200cyc L2 latency.
  uint4 p0[4], p1[4];
#pragma unroll
  for (int s = 0; s < 4; ++s) {
    p0[s] = wswz[s * 128 + lane];
    p1[s] = wswz[s * 128 + 64 + lane];
  }
  for (int ct = 0; ct < K / 16; ct += 4) {
#pragma unroll
    for (int s = 0; s < 4; ++s) {
      const uint4 cb0 = p0[s], cb1 = p1[s];
      if (ct + s + 4 < K / 16) {
        p0[s] = wswz[(ct + s + 4) * 128 + lane];
        p1[s] = wswz[(ct + s + 4) * 128 + 64 + lane];
      }
      process(ct + s, cb0, cb1);
    }
  }

  // Cross-lane argmax over the 16 cols; C/D row = 4*g+j, col = nl.
  float ddist = 0.f;
#pragma unroll
  for (int tt = 0; tt < 4; ++tt) {
#pragma unroll
    for (int j = 0; j < 4; ++j) {
      float b = best[tt][j];
      unsigned bi = bidx[tt][j];
#pragma unroll
      for (int off = 1; off < 16; off <<= 1) {
        float ob = __shfl_xor(b, off, 64);
        unsigned oi = __shfl_xor(bi, off, 64);
        if (ob > b || (ob == b && oi < bi)) { b = ob; bi = oi; }
      }
      if (nl == 0) {
        int tl = wv * 64 + tt * 16 + 4 * g + j;
        s_idx[tl] = bi;
        atomicAdd(&s_hist[bi], 1u);
        ddist = fmaf(-2.0f, b, ddist);  // dist = wsq - 2*dot >= 0
      }
    }
  }

  // Block-reduce SSE contribution: sum(x^2) + sum(dist_best).
  float sv = xsq + ddist;
#pragma unroll
  for (int off = 32; off > 0; off >>= 1) sv += __shfl_down(sv, off, 64);
  if (lane == 0) s_red[wv] = sv;
  __syncthreads();  // also publishes s_idx / orders s_hist atomics
  if (tid == 0) atomicAdd(sse, (double)((s_red[0] + s_red[1]) + (s_red[2] + s_red[3])));

  for (int i = tid; i < K; i += 256) {
    unsigned h = s_hist[i];
    if (h) atomicAdd(&counts[i], h);
  }

  // out = W[idx] (fp32 gather; == x + (q - x) to <=1 ulp).
  const int d4 = tid & 15;
#pragma unroll
  for (int tk = 0; tk < TOKB / 16; ++tk) {
    int tl = tk * 16 + (tid >> 4);
    unsigned ci = s_idx[tl];
    float4 q = *reinterpret_cast<const float4*>(Wf + ci * D + d4 * 4);
    *reinterpret_cast<float4*>(out + (size_t)(tokwg + tl) * D + d4 * 4) = q;
  }

  // ---- fused final: last block to finish does the tail reduction ----
  // NO __threadfence (R7 lesson): counts/sse are device-scope atomic RMWs at
  // the coherence point; the compiler's s_waitcnt vmcnt(0) before s_barrier
  // orders them before the ticket RMW. An agent fence would buffer_inv the
  // XCD L2 and stall every in-flight block (the R4/R5 170us regression).
  __syncthreads();
  if (tid == 0) {
    unsigned t = atomicAdd(ticket, 1u);
    s_last = (t == gridDim.x - 1) ? 1u : 0u;
  }
  __syncthreads();
  if (s_last) {
    const float inv_n = 1.0f / (float)n_tokens;
    float s = 0.f;
    unsigned u = 0;
    for (int c = tid; c < K; c += 256) {
      unsigned cnt = atomicAdd(&counts[c], 0u);  // coherent RMW read
      float p = (float)cnt * inv_n;
      s += p * logf(p + 1e-10f);
      u += (cnt >= 1u) ? 1u : 0u;
    }
#pragma unroll
    for (int off = 32; off > 0; off >>= 1) {
      s += __shfl_down(s, off, 64);
      u += __shfl_down(u, off, 64);
    }
    if (lane == 0) { s_red[wv] = s; s_ured[wv] = u; }
    __syncthreads();
    if (tid == 0) {
      double sv2 = atomicAdd(sse, 0.0);  // coherent read of final SSE
      float s2 = (s_red[0] + s_red[1]) + (s_red[2] + s_red[3]);
      unsigned u2 = s_ured[0] + s_ured[1] + s_ured[2] + s_ured[3];
      double mean = sv2 / ((double)n_tokens * (double)D);
      float* out_tail = out + (size_t)n_tokens * D;
      out_tail[0] = 3.0f * (float)mean;  // q_latent + 2*e_latent
      out_tail[1] = expf(-s2);           // perplexity
      out_tail[2] = (float)u2;           // usage
    }
  }
}

extern "C" void kernel_launch(void* const* d_in, const int* in_sizes, int n_in,
                              void* d_out, int out_size, void* d_ws, size_t ws_size,
                              hipStream_t stream) {
  const float* x = (const float*)d_in[0];
  const float* W = (const float*)d_in[1];
  float* out = (float*)d_out;

  unsigned* counts = (unsigned*)d_ws;
  double* sse = (double*)((char*)d_ws + 4096);
  unsigned* ticket = (unsigned*)((char*)d_ws + 5120);
  float* wnh = (float*)((char*)d_ws + 8192);
  uint4* wswz = (uint4*)((char*)d_ws + 16384);

  const int n_tokens = in_sizes[0] / D;  // 131072
  const int blocks = n_tokens / TOKB;    // 512

  vq_init<<<K * 8 / 256, 256, 0, stream>>>(W, counts, wnh, sse, ticket, wswz);
  vq_main<<<blocks, 256, 0, stream>>>(x, W, wswz, wnh, counts, sse, ticket,
                                      out, n_tokens);
}